// Round 12
// baseline (221.194 us; speedup 1.0000x reference)
//
#include <hip/hip_runtime.h>
#include <math.h>

#define B_ 2
#define S_ 2048
#define D_ 1024
#define H_ 16
#define HD_ 64

#define LOG2E 1.44269504088896f
#define LN2   0.69314718055994531f

typedef __bf16 bf16_t;
typedef bf16_t bf16x8 __attribute__((ext_vector_type(8)));
typedef bf16_t bf16x4v __attribute__((ext_vector_type(4)));
typedef float f32x4 __attribute__((ext_vector_type(4)));

#if defined(__has_builtin)
#  if __has_builtin(__builtin_amdgcn_exp2f)
#    define EXP2(x) __builtin_amdgcn_exp2f(x)
#  else
#    define EXP2(x) __expf((x) * LN2)
#  endif
#else
#  define EXP2(x) __expf((x) * LN2)
#endif

#define GLOBAL_LOAD_LDS16(gp, lp)                                              \
    __builtin_amdgcn_global_load_lds(                                          \
        (const __attribute__((address_space(1))) void*)(gp),                   \
        (__attribute__((address_space(3))) void*)(lp), 16, 0, 0)

// ============================================================================
// fp32 -> bf16 cast, 1D grid. kbias in exp2 domain (-8*log2e / -1e30).
// ============================================================================
__global__ __launch_bounds__(256) void cvt_kernel(
    const float* __restrict__ q, const float* __restrict__ k,
    const float* __restrict__ v, const float* __restrict__ wq,
    const float* __restrict__ wk, const float* __restrict__ wv,
    const int* __restrict__ msk,
    bf16_t* __restrict__ qb, bf16_t* __restrict__ kb, bf16_t* __restrict__ vb,
    bf16_t* __restrict__ wqb, bf16_t* __restrict__ wkb, bf16_t* __restrict__ wvb,
    float* __restrict__ kbias)
{
    const int bid = blockIdx.x;
    const float* src;
    bf16_t* dst;
    int x;

    if (bid < 12288) {
        int y = bid >> 12;
        x = bid & 4095;
        src = (y == 0) ? q : (y == 1) ? k : v;
        dst = (y == 0) ? qb : (y == 1) ? kb : vb;
    } else if (bid < 15360) {
        int y = (bid - 12288) >> 10;
        x = (bid - 12288) & 1023;
        src = (y == 0) ? wq : (y == 1) ? wk : wv;
        dst = (y == 0) ? wqb : (y == 1) ? wkb : wvb;
    } else {
        size_t idx = ((size_t)(bid - 15360) * 256 + threadIdx.x) * 4;
        int4 mi = *(const int4*)(msk + idx);
        const float vb_ = -8.0f * LOG2E;
        float4 o4;
        o4.x = mi.x ? vb_ : -1e30f;
        o4.y = mi.y ? vb_ : -1e30f;
        o4.z = mi.z ? vb_ : -1e30f;
        o4.w = mi.w ? vb_ : -1e30f;
        *(float4*)(kbias + idx) = o4;
        return;
    }

    size_t idx = ((size_t)x * 256 + threadIdx.x) * 4;
    float4 f = *(const float4*)(src + idx);
    bf16x4v o;
    o[0] = (bf16_t)f.x; o[1] = (bf16_t)f.y;
    o[2] = (bf16_t)f.z; o[3] = (bf16_t)f.w;
    *(bf16x4v*)(dst + idx) = o;
}

// ============================================================================
// Fused projection GEMM (unchanged from R10).
// ============================================================================
__global__ __launch_bounds__(256) void proj_mfma(
    const bf16_t* __restrict__ X0, const bf16_t* __restrict__ X1,
    const bf16_t* __restrict__ X2, const bf16_t* __restrict__ W0,
    const bf16_t* __restrict__ W1, const bf16_t* __restrict__ W2,
    const float* __restrict__ b0, const float* __restrict__ b1,
    const float* __restrict__ b2, bf16_t* __restrict__ o0,
    bf16_t* __restrict__ o1, bf16_t* __restrict__ o2)
{
    __shared__ __align__(16) bf16_t As[128 * 32];
    __shared__ __align__(16) bf16_t Bs[128 * 32];

    const int z = blockIdx.z;
    const bf16_t* X = (z == 0) ? X0 : (z == 1) ? X1 : X2;
    const bf16_t* W = (z == 0) ? W0 : (z == 1) ? W1 : W2;
    const float* bias = (z == 0) ? b0 : (z == 1) ? b1 : b2;
    bf16_t* out = (z == 0) ? o0 : (z == 1) ? o1 : o2;

    const bf16_t* Amat = (z == 2) ? X : W;
    const bf16_t* Bmat = (z == 2) ? W : X;
    const int arow0 = (z == 2) ? blockIdx.x * 128 : blockIdx.y * 128;
    const int brow0 = (z == 2) ? blockIdx.y * 128 : blockIdx.x * 128;

    const int tid  = threadIdx.x;
    const int w    = tid >> 6;
    const int lane = tid & 63;
    const int L    = lane & 15;
    const int quad = lane >> 4;
    const int wr   = (w >> 1) * 64;
    const int wc   = (w & 1) * 64;

    const int lr = lane >> 2;
    const int lc = (lane & 3) * 8;

    f32x4 acc[4][4];
    #pragma unroll
    for (int i = 0; i < 4; ++i)
        #pragma unroll
        for (int j = 0; j < 4; ++j) {
            acc[i][j][0] = 0.f; acc[i][j][1] = 0.f;
            acc[i][j][2] = 0.f; acc[i][j][3] = 0.f;
        }

    for (int k0 = 0; k0 < D_; k0 += 32) {
        __syncthreads();
        #pragma unroll
        for (int i = 0; i < 2; ++i) {
            const int rA = i * 64 + w * 16;
            GLOBAL_LOAD_LDS16(Amat + (size_t)(arow0 + rA + lr) * D_ + k0 + lc,
                              &As[rA * 32]);
            GLOBAL_LOAD_LDS16(Bmat + (size_t)(brow0 + rA + lr) * D_ + k0 + lc,
                              &Bs[rA * 32]);
        }
        __syncthreads();

        bf16x8 aF[4], bF[4];
        #pragma unroll
        for (int t = 0; t < 4; ++t) {
            aF[t] = *(const bf16x8*)&As[(wr + t * 16 + L) * 32 + quad * 8];
            bF[t] = *(const bf16x8*)&Bs[(wc + t * 16 + L) * 32 + quad * 8];
        }
        #pragma unroll
        for (int mt = 0; mt < 4; ++mt)
            #pragma unroll
            for (int nt = 0; nt < 4; ++nt)
                acc[mt][nt] = __builtin_amdgcn_mfma_f32_16x16x32_bf16(
                    aF[mt], bF[nt], acc[mt][nt], 0, 0, 0);
    }

    if (z == 2) {
        #pragma unroll
        for (int nt = 0; nt < 4; ++nt) {
            const int j  = brow0 + wc + nt * 16 + L;
            const float bval = bias[j];
            const int h  = j >> 6;
            const int hd = j & 63;
            #pragma unroll
            for (int mt = 0; mt < 4; ++mt) {
                const int n = arow0 + wr + mt * 16 + quad * 4;
                const int b = n >> 11;
                const int s = n & (S_ - 1);
                bf16x4v r4;
                #pragma unroll
                for (int r = 0; r < 4; ++r)
                    r4[r] = (bf16_t)(acc[mt][nt][r] + bval);
                *(bf16x4v*)(out + (((size_t)b * H_ + h) * HD_ + hd) * S_ + s) = r4;
            }
        }
    } else {
        const float oscale = (z == 0) ? 0.125f * LOG2E : 1.0f;
        #pragma unroll
        for (int mt = 0; mt < 4; ++mt) {
            const int j4 = arow0 + wr + mt * 16 + quad * 4;
            const int h  = j4 >> 6;
            const int hd = j4 & 63;
            const f32x4 b4 = *(const f32x4*)(bias + j4);
            #pragma unroll
            for (int nt = 0; nt < 4; ++nt) {
                const int n = brow0 + wc + nt * 16 + L;
                const int b = n >> 11;
                const int s = n & (S_ - 1);
                bf16x4v r4;
                #pragma unroll
                for (int r = 0; r < 4; ++r)
                    r4[r] = (bf16_t)((acc[mt][nt][r] + b4[r]) * oscale);
                *(bf16x4v*)(out + ((((size_t)b * H_ + h) * S_ + s) * HD_) + hd) = r4;
            }
        }
    }
}

// ============================================================================
// KEY-SPLIT flash attention using ONLY the verified 16x16x32 MFMA.
// Wave w owns keys w*16..w*16+15 of each 64-key tile, for ALL 64 q.
// S^T = mfma(aK, aQ): lane L reg r = P[q=L][key=quad*4+r]  (verified C-layout)
// PV via ZERO-PADDED 16x16x32: A elem j(0..3)=P[q][key=quad*4+j] at
// k=quad*8+j, elems 4..7 = 0; B elem j(0..3)=V[key=quad*4+j][d], elems
// 4..7 = 0. Every key hits exactly one consistent contraction index ->
// exact P.V (no unverified K=16 layout). P never touches LDS.
// Fixed-shift softmax => per-wave (o,l) partials combine by summation once.
// Q-tile 64 -> grid 1024; launch_bounds(256,3) -> 12 waves/CU.
// ============================================================================
__global__ __launch_bounds__(256, 3) void attn_kernel(
    const bf16_t* __restrict__ Q, const bf16_t* __restrict__ K,
    const bf16_t* __restrict__ Vt, const float* __restrict__ kbias,
    const int* __restrict__ mask, float* __restrict__ out)
{
    constexpr int LD = 72;      // bf16 row stride (Ks/Vs)
    constexpr int OD = 68;      // f32 row stride (obuf)
    __shared__ bf16_t Ks[64 * LD];
    __shared__ bf16_t Vs[64 * LD];        // [d][key]
    __shared__ float  obuf[64 * OD];      // [d][q] reduction buffer
    __shared__ float  lbuf[4][64];        // per-wave l partials

    const int tid  = threadIdx.x;
    const int w    = tid >> 6;
    const int lane = tid & 63;
    const int L    = lane & 15;
    const int quad = lane >> 4;
    const int h    = blockIdx.y;
    const int b    = blockIdx.z;
    const int bh   = b * H_ + h;
    const int q0   = blockIdx.x * 64;

    const bf16_t* kbase = K  + (size_t)bh * S_ * HD_;
    const bf16_t* vbase = Vt + (size_t)bh * HD_ * S_;
    const float*  bbase = kbias + b * S_;
    const int*    mrow  = mask + b * S_;

    const int sr  = tid >> 3;           // 0..31
    const int sc2 = (tid & 7) * 8;      // 0..56

    // Q fragments (B-operand for S^T): all 4 q-groups, one-time from global
    bf16x8 aQ[4][2];
    #pragma unroll
    for (int qg = 0; qg < 4; ++qg) {
        const bf16_t* qp = Q + ((size_t)bh * S_ + q0 + qg * 16 + L) * HD_;
        aQ[qg][0] = *(const bf16x8*)(qp + quad * 8);
        aQ[qg][1] = *(const bf16x8*)(qp + 32 + quad * 8);
    }

    f32x4 o[4][4];                       // [qg][dg]: q=qg*16+quad*4+r, d=dg*16+L
    #pragma unroll
    for (int qg = 0; qg < 4; ++qg)
        #pragma unroll
        for (int dg = 0; dg < 4; ++dg) {
            o[qg][dg][0]=0.f; o[qg][dg][1]=0.f; o[qg][dg][2]=0.f; o[qg][dg][3]=0.f;
        }
    float l_[4] = {0.f, 0.f, 0.f, 0.f};  // partial l for q=qg*16+L over wave keys

    // ---- prefetch tile 0 ----
    bf16x8 kr0, kr1, vr0, vr1;
    f32x4  bias_n;
    {
        kr0 = *(const bf16x8*)(kbase + (size_t)sr * HD_ + sc2);
        kr1 = *(const bf16x8*)(kbase + (size_t)(sr + 32) * HD_ + sc2);
        vr0 = *(const bf16x8*)(vbase + (size_t)sr * S_ + sc2);
        vr1 = *(const bf16x8*)(vbase + (size_t)(sr + 32) * S_ + sc2);
        bias_n = *(const f32x4*)(bbase + w * 16 + quad * 4);
    }

    for (int kt = 0; kt < S_; kt += 64) {
        __syncthreads();    // previous tile's LDS reads complete
        *(bf16x8*)&Ks[sr * LD + sc2]        = kr0;
        *(bf16x8*)&Ks[(sr + 32) * LD + sc2] = kr1;
        *(bf16x8*)&Vs[sr * LD + sc2]        = vr0;
        *(bf16x8*)&Vs[(sr + 32) * LD + sc2] = vr1;
        f32x4 bias_c = bias_n;
        __syncthreads();    // staging visible

        if (kt + 64 < S_) {
            const int kn = kt + 64;
            kr0 = *(const bf16x8*)(kbase + (size_t)(kn + sr) * HD_ + sc2);
            kr1 = *(const bf16x8*)(kbase + (size_t)(kn + sr + 32) * HD_ + sc2);
            vr0 = *(const bf16x8*)(vbase + (size_t)sr * S_ + kn + sc2);
            vr1 = *(const bf16x8*)(vbase + (size_t)(sr + 32) * S_ + kn + sc2);
            bias_n = *(const f32x4*)(bbase + kn + w * 16 + quad * 4);
        }

        // K fragments: this wave's 16-key slice only
        bf16x8 aK0 = *(const bf16x8*)&Ks[(w * 16 + L) * LD + quad * 8];
        bf16x8 aK1 = *(const bf16x8*)&Ks[(w * 16 + L) * LD + 32 + quad * 8];

        // ---- S^T + exp + in-register pack to zero-padded A operands ----
        bf16x8 pA[4];
        #pragma unroll
        for (int qg = 0; qg < 4; ++qg) {
            f32x4 z;
            z[0] = bias_c[0]; z[1] = bias_c[1];
            z[2] = bias_c[2]; z[3] = bias_c[3];
            z = __builtin_amdgcn_mfma_f32_16x16x32_bf16(aK0, aQ[qg][0], z, 0, 0, 0);
            z = __builtin_amdgcn_mfma_f32_16x16x32_bf16(aK1, aQ[qg][1], z, 0, 0, 0);
            float e0 = EXP2(z[0]);
            float e1 = EXP2(z[1]);
            float e2 = EXP2(z[2]);
            float e3 = EXP2(z[3]);
            l_[qg] += (e0 + e1) + (e2 + e3);
            bf16x8 p8;
            p8[0] = (bf16_t)e0; p8[1] = (bf16_t)e1;
            p8[2] = (bf16_t)e2; p8[3] = (bf16_t)e3;
            p8[4] = (bf16_t)0.f; p8[5] = (bf16_t)0.f;
            p8[6] = (bf16_t)0.f; p8[7] = (bf16_t)0.f;
            pA[qg] = p8;
        }

        // ---- PV: zero-padded 16x16x32, B = V[key=quad*4+j][d=L] at j=0..3
        #pragma unroll
        for (int dg = 0; dg < 4; ++dg) {
            bf16x4v v4 = *(const bf16x4v*)&Vs[(dg * 16 + L) * LD + w * 16 + quad * 4];
            bf16x8 bv8;
            bv8[0] = v4[0]; bv8[1] = v4[1]; bv8[2] = v4[2]; bv8[3] = v4[3];
            bv8[4] = (bf16_t)0.f; bv8[5] = (bf16_t)0.f;
            bv8[6] = (bf16_t)0.f; bv8[7] = (bf16_t)0.f;
            #pragma unroll
            for (int qg = 0; qg < 4; ++qg)
                o[qg][dg] = __builtin_amdgcn_mfma_f32_16x16x32_bf16(
                    pA[qg], bv8, o[qg][dg], 0, 0, 0);
        }
    }

    // ---- l: reduce over quads (this wave's keys), publish partial ----
    #pragma unroll
    for (int qg = 0; qg < 4; ++qg) {
        float t = l_[qg];
        t += __shfl_xor(t, 16);
        t += __shfl_xor(t, 32);
        if (lane < 16) lbuf[w][qg * 16 + L] = t;
    }

    // ---- o: sequential cross-wave summation into obuf[d][q] ----
    if (w == 0) {
        #pragma unroll
        for (int qg = 0; qg < 4; ++qg)
            #pragma unroll
            for (int dg = 0; dg < 4; ++dg)
                *(f32x4*)&obuf[(dg * 16 + L) * OD + qg * 16 + quad * 4] = o[qg][dg];
    }
    __syncthreads();
    #pragma unroll
    for (int ww = 1; ww < 4; ++ww) {
        if (w == ww) {
            #pragma unroll
            for (int qg = 0; qg < 4; ++qg)
                #pragma unroll
                for (int dg = 0; dg < 4; ++dg) {
                    float* dst = &obuf[(dg * 16 + L) * OD + qg * 16 + quad * 4];
                    f32x4 t = *(const f32x4*)dst;
                    t[0] += o[qg][dg][0]; t[1] += o[qg][dg][1];
                    t[2] += o[qg][dg][2]; t[3] += o[qg][dg][3];
                    *(f32x4*)dst = t;
                }
        }
        __syncthreads();
    }

    // ---- epilogue: thread t -> q = t>>2, d-chunk (t&3)*16 ----
    const int q = tid >> 2;
    const int c = (tid & 3) * 16;
    float lt = lbuf[0][q] + lbuf[1][q] + lbuf[2][q] + lbuf[3][q];
    int qv = mrow[q0 + q];
    float inv = (qv && lt > 0.f) ? (1.0f / lt) : 0.0f;
    float* op = out + ((size_t)b * S_ + q0 + q) * D_ + h * HD_ + c;
    #pragma unroll
    for (int g = 0; g < 4; ++g) {
        f32x4 rr;
        #pragma unroll
        for (int j = 0; j < 4; ++j)
            rr[j] = obuf[(c + g * 4 + j) * OD + q] * inv;
        *(f32x4*)(op + g * 4) = rr;
    }
}

// ============================================================================
extern "C" void kernel_launch(void* const* d_in, const int* in_sizes, int n_in,
                              void* d_out, int out_size, void* d_ws, size_t ws_size,
                              hipStream_t stream)
{
    const float* q    = (const float*)d_in[0];
    const float* k    = (const float*)d_in[1];
    const float* v    = (const float*)d_in[2];
    const int*   mask = (const int*)d_in[3];
    const float* Wq   = (const float*)d_in[4];
    const float* bq   = (const float*)d_in[5];
    const float* Wk   = (const float*)d_in[6];
    const float* bk   = (const float*)d_in[7];
    const float* Wv   = (const float*)d_in[8];
    const float* bv   = (const float*)d_in[9];
    float* out = (float*)d_out;

    const size_t PE = (size_t)B_ * S_ * D_;
    const size_t WE = (size_t)D_ * D_;

    bf16_t* qb    = (bf16_t*)d_ws;
    bf16_t* kb    = qb + PE;
    bf16_t* vb    = kb + PE;
    bf16_t* wqb   = vb + PE;
    bf16_t* wkb   = wqb + WE;
    bf16_t* wvb   = wkb + WE;
    bf16_t* mq    = wvb + WE;
    bf16_t* mk    = mq + PE;
    bf16_t* vt    = mk + PE;
    float*  kbias = (float*)(vt + PE);

    cvt_kernel<<<dim3(15364), 256, 0, stream>>>(q, k, v, Wq, Wk, Wv, mask,
                                                qb, kb, vb, wqb, wkb, wvb, kbias);

    dim3 pgrid(4096 / 128, 1024 / 128, 3);
    proj_mfma<<<pgrid, 256, 0, stream>>>(qb, kb, vb, wqb, wkb, wvb,
                                         bq, bk, bv, mq, mk, vt);

    dim3 agrid(S_ / 64, H_, B_);
    attn_kernel<<<agrid, 256, 0, stream>>>(mq, mk, vt, kbias, mask, out);
}